// Round 1
// baseline (1246.169 us; speedup 1.0000x reference)
//
#include <hip/hip_runtime.h>
#include <cstdint>

#define N_ATOMS 200000
#define N_FEAT  1024
#define HDIM    256
#define N_STRUCT 2000
#define M_TILE  64
#define SCALE   1.0f

typedef __bf16 bf16x8 __attribute__((ext_vector_type(8)));
typedef float  f32x4  __attribute__((ext_vector_type(4)));

__device__ __forceinline__ void gl_lds16(const void* g, void* l) {
    __builtin_amdgcn_global_load_lds(
        (const __attribute__((address_space(1))) uint32_t*)g,
        (__attribute__((address_space(3))) uint32_t*)l, 16, 0, 0);
}

// Cast W_h1 (262144) and W_h2 (65536) to bf16 in workspace.
__global__ void convert_w(const float* __restrict__ W1, const float* __restrict__ W2,
                          __bf16* __restrict__ w1b, __bf16* __restrict__ w2b) {
    int i = blockIdx.x * 256 + threadIdx.x;
    if (i < 262144) w1b[i] = (__bf16)W1[i];
    int j = i - 262144;
    if (j >= 0 && j < 65536) w2b[j] = (__bf16)W2[j];
}

__global__ __launch_bounds__(256, 2) void fused_mlp(
    const float* __restrict__ ps, const int* __restrict__ numbers, const int* __restrict__ batch,
    const float* __restrict__ W_comp, const float* __restrict__ W_psl, const float* __restrict__ W_out,
    const __bf16* __restrict__ w1b, const __bf16* __restrict__ w2b,
    float* __restrict__ out)
{
    // LDS: A1 4KB | B (shared layer1/layer2 k-chunk) 16KB | A2 (h1, padded) 33KB | evec
    __shared__ __align__(16) __bf16 A1[M_TILE * 32];      // [64][32] row-major
    __shared__ __align__(16) __bf16 Bb[HDIM * 32];        // [256 n][32 k]
    __shared__ __align__(16) __bf16 A2[M_TILE * 264];     // [64][256+8 pad]
    __shared__ float evec[M_TILE];

    const int t    = threadIdx.x;
    const int wave = t >> 6;
    const int lane = t & 63;
    const int quad = lane >> 4;
    const int l15  = lane & 15;
    const int atom0 = blockIdx.x * M_TILE;

    const int r_a  = t >> 2;          // staging row 0..63
    const int ks_a = (t & 3) * 8;     // staging k-sub 0/8/16/24
    const float* psrow = ps + (size_t)(atom0 + r_a) * N_FEAT + ks_a;

    f32x4 acc[4][4];
#pragma unroll
    for (int i = 0; i < 4; ++i)
#pragma unroll
        for (int j = 0; j < 4; ++j) acc[i][j] = (f32x4){0.f, 0.f, 0.f, 0.f};

    float psl_acc = 0.f;

    // ---------------- layer 1: h1 = silu(ps @ W1^T), tile [64][256] ----------------
    for (int k0 = 0; k0 < N_FEAT; k0 += 32) {
        // A-chunk: fp32 load -> psl partial -> bf16 -> LDS
        float4 f0 = *(const float4*)(psrow + k0);
        float4 f1 = *(const float4*)(psrow + k0 + 4);
        float4 w0 = *(const float4*)(W_psl + k0 + ks_a);
        float4 w1 = *(const float4*)(W_psl + k0 + ks_a + 4);
        psl_acc += f0.x * w0.x + f0.y * w0.y + f0.z * w0.z + f0.w * w0.w
                 + f1.x * w1.x + f1.y * w1.y + f1.z * w1.z + f1.w * w1.w;
        bf16x8 av;
        av[0] = (__bf16)f0.x; av[1] = (__bf16)f0.y; av[2] = (__bf16)f0.z; av[3] = (__bf16)f0.w;
        av[4] = (__bf16)f1.x; av[5] = (__bf16)f1.y; av[6] = (__bf16)f1.z; av[7] = (__bf16)f1.w;
        *(bf16x8*)&A1[t * 8] = av;    // byte offset t*16, matches [64][32] row-major

        // B-chunk: async global->LDS, 4 phases x 16B/thread = [256 n][32 k]
#pragma unroll
        for (int p = 0; p < 4; ++p) {
            const __bf16* gsrc = w1b + (size_t)(p * 64 + r_a) * N_FEAT + k0 + ks_a;
            gl_lds16(gsrc, &Bb[p * 2048 + t * 8]);
        }
        __syncthreads();

        bf16x8 afrag[4];
#pragma unroll
        for (int mt = 0; mt < 4; ++mt)
            afrag[mt] = *(const bf16x8*)&A1[(mt * 16 + l15) * 32 + quad * 8];
#pragma unroll
        for (int nt = 0; nt < 4; ++nt) {
            int n = wave * 64 + nt * 16 + l15;
            bf16x8 bfrag = *(const bf16x8*)&Bb[n * 32 + quad * 8];
#pragma unroll
            for (int mt = 0; mt < 4; ++mt)
                acc[mt][nt] = __builtin_amdgcn_mfma_f32_16x16x32_bf16(afrag[mt], bfrag, acc[mt][nt], 0, 0, 0);
        }
        __syncthreads();
    }

    // psl reduce over the 4 staging threads per row
    psl_acc += __shfl_xor(psl_acc, 1);
    psl_acc += __shfl_xor(psl_acc, 2);
    if ((t & 3) == 0) evec[r_a] = psl_acc;

    // silu + store h1 -> A2 (bf16), re-zero acc
#pragma unroll
    for (int mt = 0; mt < 4; ++mt)
#pragma unroll
        for (int nt = 0; nt < 4; ++nt) {
            int n = wave * 64 + nt * 16 + l15;
#pragma unroll
            for (int rg = 0; rg < 4; ++rg) {
                float x = acc[mt][nt][rg];
                float s = x / (1.f + __expf(-x));
                A2[(mt * 16 + quad * 4 + rg) * 264 + n] = (__bf16)s;
                acc[mt][nt][rg] = 0.f;
            }
        }
    __syncthreads();

    // ---------------- layer 2: h2pre = h1 @ W2^T, tile [64][256] ----------------
    for (int k0 = 0; k0 < HDIM; k0 += 32) {
#pragma unroll
        for (int p = 0; p < 4; ++p) {
            const __bf16* gsrc = w2b + (size_t)(p * 64 + r_a) * HDIM + k0 + ks_a;
            gl_lds16(gsrc, &Bb[p * 2048 + t * 8]);
        }
        __syncthreads();
        bf16x8 afrag[4];
#pragma unroll
        for (int mt = 0; mt < 4; ++mt)
            afrag[mt] = *(const bf16x8*)&A2[(mt * 16 + l15) * 264 + k0 + quad * 8];
#pragma unroll
        for (int nt = 0; nt < 4; ++nt) {
            int n = wave * 64 + nt * 16 + l15;
            bf16x8 bfrag = *(const bf16x8*)&Bb[n * 32 + quad * 8];
#pragma unroll
            for (int mt = 0; mt < 4; ++mt)
                acc[mt][nt] = __builtin_amdgcn_mfma_f32_16x16x32_bf16(afrag[mt], bfrag, acc[mt][nt], 0, 0, 0);
        }
        __syncthreads();
    }

    // ---------------- layer 3: psnn = silu(h2pre) . W_out, reduce ----------------
    float pr[4][4];
#pragma unroll
    for (int mt = 0; mt < 4; ++mt)
#pragma unroll
        for (int rg = 0; rg < 4; ++rg) pr[mt][rg] = 0.f;

#pragma unroll
    for (int nt = 0; nt < 4; ++nt) {
        int n = wave * 64 + nt * 16 + l15;
        float wv = W_out[n];
#pragma unroll
        for (int mt = 0; mt < 4; ++mt)
#pragma unroll
            for (int rg = 0; rg < 4; ++rg) {
                float x = acc[mt][nt][rg];
                pr[mt][rg] += (x / (1.f + __expf(-x))) * wv;
            }
    }
    // reduce across the 16 n-lanes of each quad-group
#pragma unroll
    for (int mask = 1; mask <= 8; mask <<= 1)
#pragma unroll
        for (int mt = 0; mt < 4; ++mt)
#pragma unroll
            for (int rg = 0; rg < 4; ++rg)
                pr[mt][rg] += __shfl_xor(pr[mt][rg], mask);
    if (l15 == 0) {
#pragma unroll
        for (int mt = 0; mt < 4; ++mt)
#pragma unroll
            for (int rg = 0; rg < 4; ++rg)
                atomicAdd(&evec[mt * 16 + quad * 4 + rg], pr[mt][rg]);
    }
    __syncthreads();

    // ---------------- per-atom energy, segmented scan (batch sorted), atomics ----------------
    if (t < M_TILE) {
        int atom = atom0 + t;
        int b = batch[atom];
        float e = W_comp[numbers[atom]] + SCALE * evec[t];
#pragma unroll
        for (int d = 1; d < 64; d <<= 1) {
            float vu = __shfl_up(e, d);
            int   bu = __shfl_up(b, d);
            if (lane >= d && bu == b) e += vu;
        }
        int bn = __shfl_down(b, 1);
        if (lane == 63 || bn != b) atomicAdd(&out[b], e);
    }
}

extern "C" void kernel_launch(void* const* d_in, const int* in_sizes, int n_in,
                              void* d_out, int out_size, void* d_ws, size_t ws_size,
                              hipStream_t stream) {
    const float* ps     = (const float*)d_in[0];
    const int*   numbers= (const int*)d_in[1];
    const int*   batch  = (const int*)d_in[2];
    const float* W_comp = (const float*)d_in[3];
    const float* W_psl  = (const float*)d_in[4];
    const float* W_h1   = (const float*)d_in[5];
    const float* W_h2   = (const float*)d_in[6];
    const float* W_out  = (const float*)d_in[7];
    float* out = (float*)d_out;

    __bf16* w1b = (__bf16*)d_ws;            // 262144 bf16
    __bf16* w2b = w1b + 262144;             // 65536 bf16  (total 640 KB of ws)

    hipMemsetAsync(d_out, 0, (size_t)out_size * sizeof(float), stream);
    convert_w<<<1280, 256, 0, stream>>>(W_h1, W_h2, w1b, w2b);
    fused_mlp<<<3125, 256, 0, stream>>>(ps, numbers, batch, W_comp, W_psl, W_out, w1b, w2b, out);
}

// Round 2
// 1206.531 us; speedup vs baseline: 1.0329x; 1.0329x over previous
//
#include <hip/hip_runtime.h>
#include <cstdint>

#define N_ATOMS 200000
#define N_FEAT  1024
#define HDIM    256
#define N_STRUCT 2000
#define M_TILE  64
#define SCALE   1.0f
#define A1_LD   40   // padded leading dim (32 valid) -> 2-way banks on b128 reads

typedef __bf16 bf16x8 __attribute__((ext_vector_type(8)));
typedef float  f32x4  __attribute__((ext_vector_type(4)));

__device__ __forceinline__ void gl_lds16(const void* g, void* l) {
    __builtin_amdgcn_global_load_lds(
        (const __attribute__((address_space(1))) uint32_t*)g,
        (__attribute__((address_space(3))) uint32_t*)l, 16, 0, 0);
}

__device__ __forceinline__ float silu(float x) { return x / (1.f + __expf(-x)); }

// Cast W_h1 (262144) and W_h2 (65536) to bf16 in workspace.
__global__ void convert_w(const float* __restrict__ W1, const float* __restrict__ W2,
                          __bf16* __restrict__ w1b, __bf16* __restrict__ w2b) {
    int i = blockIdx.x * 256 + threadIdx.x;
    if (i < 262144) w1b[i] = (__bf16)W1[i];
    int j = i - 262144;
    if (j >= 0 && j < 65536) w2b[j] = (__bf16)W2[j];
}

__global__ __launch_bounds__(256, 2) void fused_mlp(
    const float* __restrict__ ps, const int* __restrict__ numbers, const int* __restrict__ batch,
    const float* __restrict__ W_comp, const float* __restrict__ W_psl, const float* __restrict__ W_out,
    const __bf16* __restrict__ w1b, const __bf16* __restrict__ w2b,
    float* __restrict__ out)
{
    // LDS: A1 2x5KB | Bb 2x16KB | A2 33KB | evec 256B  = 75.3 KB -> 2 blocks/CU
    __shared__ __align__(16) __bf16 A1[2][M_TILE * A1_LD];
    __shared__ __align__(16) __bf16 Bb[2][HDIM * 32];
    __shared__ __align__(16) __bf16 A2[M_TILE * 264];
    __shared__ float evec[M_TILE];

    const int t    = threadIdx.x;
    const int wave = t >> 6;
    const int lane = t & 63;
    const int quad = lane >> 4;
    const int l15  = lane & 15;
    const int atom0 = blockIdx.x * M_TILE;

    const int r_a = t >> 2;                    // staging row 0..63
    const int c_a = t & 3;                     // chunk position 0..3
    const int s_a = c_a ^ ((t >> 3) & 3);      // swizzled source chunk (row = t>>2)
    const int bq  = quad ^ ((l15 >> 1) & 3);   // swizzled chunk for B reads

    const float* psrow = ps + (size_t)(atom0 + r_a) * N_FEAT + c_a * 8;
    const float* wpsl  = W_psl + c_a * 8;

    f32x4 acc[4][4];
#pragma unroll
    for (int i = 0; i < 4; ++i)
#pragma unroll
        for (int j = 0; j < 4; ++j) acc[i][j] = (f32x4){0.f, 0.f, 0.f, 0.f};

    float psl_acc = 0.f;

    // precomputed LDS element offsets (constant over k-iters)
    int a1_off[4], b_off[4];
#pragma unroll
    for (int mt = 0; mt < 4; ++mt) a1_off[mt] = (mt * 16 + l15) * A1_LD + quad * 8;
#pragma unroll
    for (int nt = 0; nt < 4; ++nt) b_off[nt] = (wave * 64 + nt * 16 + l15) * 32 + bq * 8;

    // ---------------- prologue: stage chunk 0, prefetch chunk 1 ----------------
    {
        float4 f0 = *(const float4*)(psrow);
        float4 f1 = *(const float4*)(psrow + 4);
        float4 w0 = *(const float4*)(wpsl);
        float4 w1 = *(const float4*)(wpsl + 4);
        psl_acc += f0.x * w0.x + f0.y * w0.y + f0.z * w0.z + f0.w * w0.w
                 + f1.x * w1.x + f1.y * w1.y + f1.z * w1.z + f1.w * w1.w;
        bf16x8 av;
        av[0] = (__bf16)f0.x; av[1] = (__bf16)f0.y; av[2] = (__bf16)f0.z; av[3] = (__bf16)f0.w;
        av[4] = (__bf16)f1.x; av[5] = (__bf16)f1.y; av[6] = (__bf16)f1.z; av[7] = (__bf16)f1.w;
        *(bf16x8*)&A1[0][r_a * A1_LD + c_a * 8] = av;
#pragma unroll
        for (int p = 0; p < 4; ++p)
            gl_lds16(w1b + (size_t)(p * 64 + r_a) * N_FEAT + s_a * 8, &Bb[0][p * 2048 + t * 8]);
    }
    float4 g0 = *(const float4*)(psrow + 32);
    float4 g1 = *(const float4*)(psrow + 36);
    float4 x0 = *(const float4*)(wpsl + 32);
    float4 x1 = *(const float4*)(wpsl + 36);
    __syncthreads();

    // ---------------- layer 1: h1 = silu(ps @ W1^T), pipelined, 1 barrier/iter ----------------
    for (int i = 0; i < 32; ++i) {
        const int cur = i & 1;
        if (i < 31) {
            const int k1 = (i + 1) * 32;
#pragma unroll
            for (int p = 0; p < 4; ++p)
                gl_lds16(w1b + (size_t)(p * 64 + r_a) * N_FEAT + k1 + s_a * 8,
                         &Bb[cur ^ 1][p * 2048 + t * 8]);
        }
        bf16x8 af[4];
#pragma unroll
        for (int mt = 0; mt < 4; ++mt) af[mt] = *(const bf16x8*)&A1[cur][a1_off[mt]];
#pragma unroll
        for (int nt = 0; nt < 4; ++nt) {
            bf16x8 bf_ = *(const bf16x8*)&Bb[cur][b_off[nt]];
#pragma unroll
            for (int mt = 0; mt < 4; ++mt)
                acc[mt][nt] = __builtin_amdgcn_mfma_f32_16x16x32_bf16(af[mt], bf_, acc[mt][nt], 0, 0, 0);
        }
        if (i < 31) {
            psl_acc += g0.x * x0.x + g0.y * x0.y + g0.z * x0.z + g0.w * x0.w
                     + g1.x * x1.x + g1.y * x1.y + g1.z * x1.z + g1.w * x1.w;
            bf16x8 av;
            av[0] = (__bf16)g0.x; av[1] = (__bf16)g0.y; av[2] = (__bf16)g0.z; av[3] = (__bf16)g0.w;
            av[4] = (__bf16)g1.x; av[5] = (__bf16)g1.y; av[6] = (__bf16)g1.z; av[7] = (__bf16)g1.w;
            *(bf16x8*)&A1[cur ^ 1][r_a * A1_LD + c_a * 8] = av;
            if (i < 30) {
                const int k2 = (i + 2) * 32;
                g0 = *(const float4*)(psrow + k2);
                g1 = *(const float4*)(psrow + k2 + 4);
                x0 = *(const float4*)(wpsl + k2);
                x1 = *(const float4*)(wpsl + k2 + 4);
            }
        }
        __syncthreads();
    }

    // psl reduce over the 4 staging threads per row
    psl_acc += __shfl_xor(psl_acc, 1);
    psl_acc += __shfl_xor(psl_acc, 2);
    if (c_a == 0) evec[r_a] = psl_acc;

    // silu + transpose-store h1 -> A2 (bf16), re-zero acc
#pragma unroll
    for (int mt = 0; mt < 4; ++mt)
#pragma unroll
        for (int nt = 0; nt < 4; ++nt) {
            int n = wave * 64 + nt * 16 + l15;
#pragma unroll
            for (int rg = 0; rg < 4; ++rg) {
                float x = acc[mt][nt][rg];
                A2[(mt * 16 + quad * 4 + rg) * 264 + n] = (__bf16)silu(x);
                acc[mt][nt][rg] = 0.f;
            }
        }
    // prologue layer 2: stage B2 chunk 0
#pragma unroll
    for (int p = 0; p < 4; ++p)
        gl_lds16(w2b + (size_t)(p * 64 + r_a) * HDIM + s_a * 8, &Bb[0][p * 2048 + t * 8]);
    __syncthreads();

    // ---------------- layer 2: h2pre = h1 @ W2^T, pipelined ----------------
    for (int i = 0; i < 8; ++i) {
        const int cur = i & 1;
        if (i < 7) {
            const int k1 = (i + 1) * 32;
#pragma unroll
            for (int p = 0; p < 4; ++p)
                gl_lds16(w2b + (size_t)(p * 64 + r_a) * HDIM + k1 + s_a * 8,
                         &Bb[cur ^ 1][p * 2048 + t * 8]);
        }
        const int k0 = i * 32;
        bf16x8 af[4];
#pragma unroll
        for (int mt = 0; mt < 4; ++mt)
            af[mt] = *(const bf16x8*)&A2[(mt * 16 + l15) * 264 + k0 + quad * 8];
#pragma unroll
        for (int nt = 0; nt < 4; ++nt) {
            bf16x8 bf_ = *(const bf16x8*)&Bb[cur][b_off[nt]];
#pragma unroll
            for (int mt = 0; mt < 4; ++mt)
                acc[mt][nt] = __builtin_amdgcn_mfma_f32_16x16x32_bf16(af[mt], bf_, acc[mt][nt], 0, 0, 0);
        }
        __syncthreads();
    }

    // ---------------- layer 3: psnn = silu(h2pre) . W_out, reduce ----------------
    float pr[4][4];
#pragma unroll
    for (int mt = 0; mt < 4; ++mt)
#pragma unroll
        for (int rg = 0; rg < 4; ++rg) pr[mt][rg] = 0.f;

#pragma unroll
    for (int nt = 0; nt < 4; ++nt) {
        int n = wave * 64 + nt * 16 + l15;
        float wv = W_out[n];
#pragma unroll
        for (int mt = 0; mt < 4; ++mt)
#pragma unroll
            for (int rg = 0; rg < 4; ++rg) {
                float x = acc[mt][nt][rg];
                pr[mt][rg] += silu(x) * wv;
            }
    }
#pragma unroll
    for (int mask = 1; mask <= 8; mask <<= 1)
#pragma unroll
        for (int mt = 0; mt < 4; ++mt)
#pragma unroll
            for (int rg = 0; rg < 4; ++rg)
                pr[mt][rg] += __shfl_xor(pr[mt][rg], mask);
    if (l15 == 0) {
#pragma unroll
        for (int mt = 0; mt < 4; ++mt)
#pragma unroll
            for (int rg = 0; rg < 4; ++rg)
                atomicAdd(&evec[mt * 16 + quad * 4 + rg], pr[mt][rg]);
    }
    __syncthreads();

    // ---------------- per-atom energy, segmented scan (batch sorted), atomics ----------------
    if (t < M_TILE) {
        int atom = atom0 + t;
        int b = batch[atom];
        float e = W_comp[numbers[atom]] + SCALE * evec[t];
#pragma unroll
        for (int d = 1; d < 64; d <<= 1) {
            float vu = __shfl_up(e, d);
            int   bu = __shfl_up(b, d);
            if (lane >= d && bu == b) e += vu;
        }
        int bn = __shfl_down(b, 1);
        if (lane == 63 || bn != b) atomicAdd(&out[b], e);
    }
}

extern "C" void kernel_launch(void* const* d_in, const int* in_sizes, int n_in,
                              void* d_out, int out_size, void* d_ws, size_t ws_size,
                              hipStream_t stream) {
    const float* ps     = (const float*)d_in[0];
    const int*   numbers= (const int*)d_in[1];
    const int*   batch  = (const int*)d_in[2];
    const float* W_comp = (const float*)d_in[3];
    const float* W_psl  = (const float*)d_in[4];
    const float* W_h1   = (const float*)d_in[5];
    const float* W_h2   = (const float*)d_in[6];
    const float* W_out  = (const float*)d_in[7];
    float* out = (float*)d_out;

    __bf16* w1b = (__bf16*)d_ws;            // 262144 bf16
    __bf16* w2b = w1b + 262144;             // 65536 bf16

    hipMemsetAsync(d_out, 0, (size_t)out_size * sizeof(float), stream);
    convert_w<<<1280, 256, 0, stream>>>(W_h1, W_h2, w1b, w2b);
    fused_mlp<<<3125, 256, 0, stream>>>(ps, numbers, batch, W_comp, W_psl, W_out, w1b, w2b, out);
}